// Round 4
// baseline (268.066 us; speedup 1.0000x reference)
//
#include <hip/hip_runtime.h>

// ConnectivityLoss R4: wave-slab register-resident skeletonize.
// Wave owns 40 contiguous rows (8 groups x 5); vertical neighbor h-rows via
// __shfl +-8 (ds_bpermute, conflict-free). Only wave-boundary rows go through
// a tiny swizzled LDS dbuf (1 barrier/pass). Image borders handled EXACTLY by
// clamped-window tap-dropping (no replicate maintenance needed).

#define IMG 512
#define TW  32            // output tile width  (16 x-tiles)
#define TH  128           // output tile height (4 y-tiles)
#define SKW 34            // skeleton stash cols [11,44]
#define SKH 130           // skeleton stash rows [11,140]
#define XROW 72           // exchange row stride (floats)
#define XBUF (4*2*XROW)   // 4 waves x {top,bot}
#define NT  256

struct alignas(16) R8 { float v[8]; };

__device__ __forceinline__ float f3min(float a, float b, float c) {
    return fminf(fminf(a, b), c);
}
__device__ __forceinline__ float f3max(float a, float b, float c) {
    return fmaxf(fmaxf(a, b), c);
}

// horizontal 3-tap; le/ri via lane+-1 (adjacent 8-col strip, same rows).
// fixL/fixR: clamped-window at image cols 0/511 (drop out-of-image tap).
template<bool MN>
__device__ __forceinline__ void hrow(const R8& r, R8& h, bool fixL, bool fixR) {
    float le = __shfl_up(r.v[7], 1);
    float ri = __shfl_down(r.v[0], 1);
    if (MN) {
        h.v[0] = f3min(le,     r.v[0], r.v[1]);
        h.v[1] = f3min(r.v[0], r.v[1], r.v[2]);
        h.v[2] = f3min(r.v[1], r.v[2], r.v[3]);
        h.v[3] = f3min(r.v[2], r.v[3], r.v[4]);
        h.v[4] = f3min(r.v[3], r.v[4], r.v[5]);
        h.v[5] = f3min(r.v[4], r.v[5], r.v[6]);
        h.v[6] = f3min(r.v[5], r.v[6], r.v[7]);
        h.v[7] = f3min(r.v[6], r.v[7], ri);
        if (fixL) h.v[4] = fminf(r.v[4], r.v[5]);   // gx==0: drop left tap
        if (fixR) h.v[3] = fminf(r.v[2], r.v[3]);   // gx==511: drop right tap
    } else {
        h.v[0] = f3max(le,     r.v[0], r.v[1]);
        h.v[1] = f3max(r.v[0], r.v[1], r.v[2]);
        h.v[2] = f3max(r.v[1], r.v[2], r.v[3]);
        h.v[3] = f3max(r.v[2], r.v[3], r.v[4]);
        h.v[4] = f3max(r.v[3], r.v[4], r.v[5]);
        h.v[5] = f3max(r.v[4], r.v[5], r.v[6]);
        h.v[6] = f3max(r.v[5], r.v[6], r.v[7]);
        h.v[7] = f3max(r.v[6], r.v[7], ri);
        if (fixL) h.v[4] = fmaxf(r.v[4], r.v[5]);
        if (fixR) h.v[3] = fmaxf(r.v[2], r.v[3]);
    }
}

__global__ __launch_bounds__(NT, 2)
void skel_conn_loss(const float* __restrict__ pred,
                    const float* __restrict__ target,
                    float* __restrict__ out)
{
    __shared__ float X[2*XBUF];          // boundary-row exchange dbuf (4.6 KB)
    __shared__ float SKP[SKH*SKW];       // pred skeleton
    __shared__ float SKT[SKH*SKW];       // target skeleton
    __shared__ float red[4];

    const int tid  = threadIdx.x;
    const int wv   = tid >> 6;           // wave 0..3, owns rows 40w..40w+39
    const int lane = tid & 63;
    const int s    = lane & 7;           // 8-col strip
    const int gq   = lane >> 3;          // group 0..7 within wave (5 rows)
    const int img  = blockIdx.x >> 6;
    const int rem  = blockIdx.x & 63;
    const int ty0  = (rem >> 4) * TH;
    const int tx0  = (rem & 15) * TW;

    const int c0  = 8*s;
    const int r0  = 40*wv + 5*gq;
    const int gx0 = tx0 - 12 + c0;
    const bool xin = (tx0 > 0) && (tx0 + TW < IMG);

    const bool lB = (tx0 == 0), rB = (tx0 + TW == IMG);
    const bool tB = (ty0 == 0), bB = (ty0 + TH == IMG);
    const bool fixL = lB && (s == 1);            // col 12 == gx 0
    const bool fixR = rB && (s == 5);            // col 43 == gx 511
    const bool vfT  = tB && (wv == 0) && (gq == 2);  // row 12 == gy 0 (i==2)
    const bool vfB  = bB && (wv == 3) && (gq == 3);  // row 139 == gy 511 (i==4)
    const int  sw   = 8*s + 4*(s >> 2);          // bank-swizzled exchange col

    R8 A[5], Bv[5];
    int xb = 0;

    #pragma unroll 1
    for (int t = 0; t < 2; ++t) {
        const float* __restrict__ src =
            (t ? target : pred) + (size_t)img * (IMG * IMG);

        // ---- load strip (addresses clamped; OOB values never consumed) ----
        #pragma unroll
        for (int i = 0; i < 5; ++i) {
            int gy = min(max(ty0 - 12 + r0 + i, 0), IMG - 1);
            const float* rp = src + gy * IMG;
            if (xin) {
                *(float4*)&A[i].v[0] = *(const float4*)(rp + gx0);
                *(float4*)&A[i].v[4] = *(const float4*)(rp + gx0 + 4);
            } else {
                #pragma unroll
                for (int j = 0; j < 8; ++j)
                    A[i].v[j] = rp[min(max(gx0 + j, 0), IMG - 1)];
            }
        }

        #pragma unroll 1
        for (int it = 0; it < 5; ++it) {
            // ================= pass 1: Bv = minpool3(A) =================
            {
                R8 w[5], abh, beh;
                #pragma unroll
                for (int i = 0; i < 5; ++i) hrow<true>(A[i], w[i], fixL, fixR);
                float* Xb = X + xb * XBUF;
                if (gq == 0) {                   // wave top row h-pool
                    float* p = Xb + (2*wv) * XROW + sw;
                    *(float4*)p       = *(const float4*)&w[0].v[0];
                    *(float4*)(p + 4) = *(const float4*)&w[0].v[4];
                }
                if (gq == 7) {                   // wave bottom row h-pool
                    float* p = Xb + (2*wv + 1) * XROW + sw;
                    *(float4*)p       = *(const float4*)&w[4].v[0];
                    *(float4*)(p + 4) = *(const float4*)&w[4].v[4];
                }
                __syncthreads();
                #pragma unroll
                for (int j = 0; j < 8; ++j) {
                    abh.v[j] = __shfl_up(w[4].v[j], 8);
                    beh.v[j] = __shfl_down(w[0].v[j], 8);
                }
                if (gq == 0) {
                    if (wv) {
                        const float* p = Xb + (2*wv - 1) * XROW + sw;
                        *(float4*)&abh.v[0] = *(const float4*)p;
                        *(float4*)&abh.v[4] = *(const float4*)(p + 4);
                    } else abh = w[0];           // block edge: garbage margin
                }
                if (gq == 7) {
                    if (wv < 3) {
                        const float* p = Xb + (2*wv + 2) * XROW + sw;
                        *(float4*)&beh.v[0] = *(const float4*)p;
                        *(float4*)&beh.v[4] = *(const float4*)(p + 4);
                    } else beh = w[4];
                }
                #pragma unroll
                for (int j = 0; j < 8; ++j) {
                    Bv[0].v[j] = f3min(abh.v[j], w[0].v[j], w[1].v[j]);
                    Bv[1].v[j] = f3min(w[0].v[j], w[1].v[j], w[2].v[j]);
                    Bv[2].v[j] = vfT ? fminf(w[2].v[j], w[3].v[j])
                                     : f3min(w[1].v[j], w[2].v[j], w[3].v[j]);
                    Bv[3].v[j] = f3min(w[2].v[j], w[3].v[j], w[4].v[j]);
                    Bv[4].v[j] = vfB ? fminf(w[3].v[j], w[4].v[j])
                                     : f3min(w[3].v[j], w[4].v[j], beh.v[j]);
                }
                xb ^= 1;
            }
            // ====== pass 2: A = relu(A - relu(maxpool3(Bv) - Bv)) ======
            {
                R8 u[5], abh, beh;
                #pragma unroll
                for (int i = 0; i < 5; ++i) hrow<false>(Bv[i], u[i], fixL, fixR);
                float* Xb = X + xb * XBUF;
                if (gq == 0) {
                    float* p = Xb + (2*wv) * XROW + sw;
                    *(float4*)p       = *(const float4*)&u[0].v[0];
                    *(float4*)(p + 4) = *(const float4*)&u[0].v[4];
                }
                if (gq == 7) {
                    float* p = Xb + (2*wv + 1) * XROW + sw;
                    *(float4*)p       = *(const float4*)&u[4].v[0];
                    *(float4*)(p + 4) = *(const float4*)&u[4].v[4];
                }
                __syncthreads();
                #pragma unroll
                for (int j = 0; j < 8; ++j) {
                    abh.v[j] = __shfl_up(u[4].v[j], 8);
                    beh.v[j] = __shfl_down(u[0].v[j], 8);
                }
                if (gq == 0) {
                    if (wv) {
                        const float* p = Xb + (2*wv - 1) * XROW + sw;
                        *(float4*)&abh.v[0] = *(const float4*)p;
                        *(float4*)&abh.v[4] = *(const float4*)(p + 4);
                    } else abh = u[0];
                }
                if (gq == 7) {
                    if (wv < 3) {
                        const float* p = Xb + (2*wv + 2) * XROW + sw;
                        *(float4*)&beh.v[0] = *(const float4*)p;
                        *(float4*)&beh.v[4] = *(const float4*)(p + 4);
                    } else beh = u[4];
                }
                #define UPD(i, MXE)                                            \
                    _Pragma("unroll")                                          \
                    for (int j = 0; j < 8; ++j) {                              \
                        float mx = (MXE);                                      \
                        float ct = fmaxf(mx - Bv[i].v[j], 0.0f);               \
                        A[i].v[j] = fmaxf(A[i].v[j] - ct, 0.0f);               \
                    }
                UPD(0, f3max(abh.v[j], u[0].v[j], u[1].v[j]))
                UPD(1, f3max(u[0].v[j], u[1].v[j], u[2].v[j]))
                UPD(2, vfT ? fmaxf(u[2].v[j], u[3].v[j])
                           : f3max(u[1].v[j], u[2].v[j], u[3].v[j]))
                UPD(3, f3max(u[2].v[j], u[3].v[j], u[4].v[j]))
                UPD(4, vfB ? fmaxf(u[3].v[j], u[4].v[j])
                           : f3max(u[3].v[j], u[4].v[j], beh.v[j]))
                #undef UPD
                xb ^= 1;
            }
        }

        // ---- stash skeleton consumed region [11,140]x[11,44] to LDS ----
        {
            float* SK = t ? SKT : SKP;
            #pragma unroll
            for (int i = 0; i < 5; ++i) {
                int pr = r0 + i;
                if (pr >= 11 && pr <= 140) {
                    #pragma unroll
                    for (int j = 0; j < 8; ++j) {
                        int pc = c0 + j;
                        if (pc >= 11 && pc <= 44)
                            SK[(pr - 11) * SKW + (pc - 11)] = A[i].v[j];
                    }
                }
            }
        }
    }
    __syncthreads();

    // ---- epilogue: sumpool3 + indicators + weighted squared diff ----
    float acc = 0.0f;
    #pragma unroll 1
    for (int k = 0; k < 16; ++k) {
        int e  = k * NT + tid;              // 0..4095
        int ly = e >> 5, lx = e & 31;
        int gy = ty0 + ly, gx = tx0 + lx;
        int base = (ly + 1) * SKW + (lx + 1);
        float ps = SKP[base], ts = SKT[base];
        float pn = 0.0f, tn = 0.0f;
        #pragma unroll
        for (int dy = -1; dy <= 1; ++dy) {
            if ((unsigned)(gy + dy) >= IMG) continue;
            #pragma unroll
            for (int dx = -1; dx <= 1; ++dx) {
                if ((unsigned)(gx + dx) >= IMG) continue;
                int o = base + dy * SKW + dx;
                pn += SKP[o];
                tn += SKT[o];
            }
        }
        float pon = (ps > 0.5f) ? 1.0f : 0.0f;
        float ton = (ts > 0.5f) ? 1.0f : 0.0f;
        float pe = (pn == 2.0f) ? pon : 0.0f;
        float te = (tn == 2.0f) ? ton : 0.0f;
        float pc = (pn >= 4.0f) ? pon : 0.0f;
        float tc = (tn >= 4.0f) ? ton : 0.0f;
        float ds = ps - ts, de = pe - te, dc = pc - tc;
        acc += 0.6f * ds * ds + 0.2f * (de * de + dc * dc);
    }

    #pragma unroll
    for (int off = 32; off >= 1; off >>= 1)
        acc += __shfl_down(acc, off, 64);
    if ((tid & 63) == 0) red[tid >> 6] = acc;
    __syncthreads();
    if (tid == 0) {
        float sum = red[0] + red[1] + red[2] + red[3];
        atomicAdd(out, sum * (1.0f / 8388608.0f));  // N = 32*512*512 = 2^23
    }
}

extern "C" void kernel_launch(void* const* d_in, const int* in_sizes, int n_in,
                              void* d_out, int out_size, void* d_ws, size_t ws_size,
                              hipStream_t stream) {
    const float* pred   = (const float*)d_in[0];
    const float* target = (const float*)d_in[1];
    float* out = (float*)d_out;
    hipMemsetAsync(d_out, 0, sizeof(float) * (out_size > 0 ? out_size : 1), stream);
    const int nblocks = 32 * 64;   // 32 images x (4x16) tiles
    skel_conn_loss<<<nblocks, NT, 0, stream>>>(pred, target, out);
}